// Round 10
// baseline (8031.146 us; speedup 1.0000x reference)
//
#include <hip/hip_runtime.h>

typedef unsigned long long u64;

#define HID 256
#define NLAYERS 5
#define BN_EPS 1e-5f
#define LDA 260   // aggL row stride in floats

// ---------------- utility ----------------

__global__ void k_zero32(unsigned int* p, int n) {
    int i = blockIdx.x * 256 + threadIdx.x;
    if (i < n) p[i] = 0u;
}

// ---------------- graph preprocessing (staged in d_out) ----------------

// Detect int64 vs int32 edge_index (odd int32 words all zero => int64).
__global__ void k_detect(const int* ei, int* flag, int E) {
    __shared__ int nz;
    if (threadIdx.x == 0) nz = 0;
    __syncthreads();
    int lim = (2 * E < 4096) ? 2 * E : 4096;
    int c = 0;
    for (int i = threadIdx.x; 2 * i + 1 < lim; i += 256) c += (ei[2 * i + 1] != 0);
    atomicAdd(&nz, c);
    __syncthreads();
    if (threadIdx.x == 0) flag[0] = (nz == 0) ? 1 : 0;
}

__global__ void k_deg(const int* ei, const int* flag, int* deg, int E, int N) {
    int e = blockIdx.x * 256 + threadIdx.x;
    if (e >= E) return;
    int w = flag[0];
    int col = w ? ei[2 * (E + e)] : ei[E + e];
    if ((unsigned)col < (unsigned)N) atomicAdd(&deg[col], 1);
}

__global__ void k_dinv(const int* deg, float* dinv, int N) {
    int n = blockIdx.x * 256 + threadIdx.x;
    if (n < N) { int d = deg[n]; dinv[n] = d > 0 ? rsqrtf((float)d) : 0.0f; }
}

__global__ void k_scan1(const int* deg, int* offs, int* bsum, int N) {
    __shared__ int s[256];
    int tid = threadIdx.x;
    int i = blockIdx.x * 256 + tid;
    int v = (i < N) ? deg[i] : 0;
    s[tid] = v;
    __syncthreads();
    for (int off = 1; off < 256; off <<= 1) {
        int t = (tid >= off) ? s[tid - off] : 0;
        __syncthreads();
        s[tid] += t;
        __syncthreads();
    }
    if (i < N) offs[i] = s[tid] - v;
    if (tid == 255) bsum[blockIdx.x] = s[tid];
}

__global__ void k_scan2(const int* bsum, int* bscan, int NB) {
    __shared__ int s[256];
    int tid = threadIdx.x;
    int v = (tid < NB) ? bsum[tid] : 0;
    s[tid] = v;
    __syncthreads();
    for (int off = 1; off < 256; off <<= 1) {
        int t = (tid >= off) ? s[tid - off] : 0;
        __syncthreads();
        s[tid] += t;
        __syncthreads();
    }
    bscan[tid] = s[tid] - v;
}

__global__ void k_scan3(int* offs, const int* bscan, int* cursor, int N, int E) {
    int i = blockIdx.x * 256 + threadIdx.x;
    if (i < N) {
        int o = offs[i] + bscan[blockIdx.x];
        offs[i] = o;
        cursor[i] = o;
    }
    if (i == 0) offs[N] = E;
}

__global__ void k_place(const int* ei, const int* flag, const float4* eattr, int* cursor,
                        int* srow, float4* sea, int E, int N) {
    int e = blockIdx.x * 256 + threadIdx.x;
    if (e >= E) return;
    int w = flag[0];
    int r = w ? ei[2 * e] : ei[e];
    int c = w ? ei[2 * (E + e)] : ei[E + e];
    if ((unsigned)c >= (unsigned)N) return;
    int p = atomicAdd(&cursor[c], 1);
    srow[p] = r;
    sea[p] = eattr[e];
}

__global__ void k_move(const int* srow, const float4* sea, const float* sdinv, const int* soffs,
                       int* rowArr, float4* eaP, float* dinvF, int* offsF, int E, int N) {
    int i = blockIdx.x * 256 + threadIdx.x;
    if (i < E) { rowArr[i] = srow[i]; eaP[i] = sea[i]; }
    if (i < N) dinvF[i] = sdinv[i];
    if (i <= N) offsF[i] = soffs[i];
}

// Integrity checks -> diag[0] bits; diag[6] = gflag copy.
__global__ void k_precheckN(const int* offsF, const int* cursor, const float* dinvF,
                            const int* gflag, int* diag, int N, int E) {
    int i = blockIdx.x * 256 + threadIdx.x;
    if (i < N) {
        if (offsF[i + 1] < offsF[i]) atomicOr(&diag[0], 1);
        if (cursor[i] != offsF[i + 1]) atomicOr(&diag[0], 2);
        float d = dinvF[i];
        if (!(d == d) || fabsf(d) > 1e10f) atomicOr(&diag[0], 4);
    }
    if (i == 0) {
        if (offsF[N] != E) atomicOr(&diag[0], 8);
        diag[6] = gflag[0];
    }
}
__global__ void k_precheckE(const int* rowArr, int* diag, int E, int N) {
    int p = blockIdx.x * 256 + threadIdx.x;
    if (p < E && (unsigned)rowArr[p] >= (unsigned)N) atomicOr(&diag[0], 16);
}

// ------- fused per-layer: agg (LDS) + fp32 GEMM + bias/ReLU + BN stats -------
// Block: 32 nodes, 256 threads (4 waves).
__global__ void MPNN_79044578115931_kernel(const float* hin, const int* offs, const int* rowArr,
                                           const float4* eaP, const float* dinv,
                                           const float* ew1, const float* ew2,
                                           const float* W, const float* bias, float* hdst,
                                           float* colsum, float* colsumsq, int* diag,
                                           int layer, int M) {
    __shared__ float aggL[32 * LDA];   // 33.28 KB
    __shared__ float Wl[16 * 256];     // 16 KB: 16 k-rows of W
    __shared__ float lsum[256];
    __shared__ float lsq[256];

    int tid = threadIdx.x;
    int lane = tid & 63, wave = tid >> 6;
    int n0 = blockIdx.x * 32;

    lsum[tid] = 0.f;
    lsq[tid] = 0.f;

    // ---- phase 1: aggregation; lane covers cols lane*4..+3 ----
    float w1v[4] = {0.f, 0.f, 0.f, 0.f};
    float w20[4] = {0.f, 0.f, 0.f, 0.f};
    float w21[4] = {0.f, 0.f, 0.f, 0.f};
    float w22[4] = {0.f, 0.f, 0.f, 0.f};
    if (lane < 32) {
        int c = lane * 4;
        for (int j = 0; j < 4; ++j) w1v[j] = ew1[c + j];
    } else {
        int cc = (lane - 32) * 4;
        for (int j = 0; j < 4; ++j) {
            w20[j] = ew2[cc + j];
            w21[j] = ew2[128 + cc + j];
            w22[j] = ew2[256 + cc + j];
        }
    }

    int badA = 0;
    for (int t = wave; t < 32; t += 4) {
        int n = n0 + t;
        float a0 = 0.f, a1 = 0.f, a2 = 0.f, a3 = 0.f;
        if (n < M) {
            float dn = dinv[n];
            int s = offs[n], e = offs[n + 1];
            for (int p = s; p < e; ++p) {
                int r = rowArr[p];
                float4 ea = eaP[p];
                float nrm = dn * dinv[r];
                float4 hv = *(const float4*)(hin + (size_t)r * HID + lane * 4);
                a0 += nrm * (hv.x + ea.w * w1v[0] + ea.x * w20[0] + ea.y * w21[0] + ea.z * w22[0]);
                a1 += nrm * (hv.y + ea.w * w1v[1] + ea.x * w20[1] + ea.y * w21[1] + ea.z * w22[1]);
                a2 += nrm * (hv.z + ea.w * w1v[2] + ea.x * w20[2] + ea.y * w21[2] + ea.z * w22[2]);
                a3 += nrm * (hv.w + ea.w * w1v[3] + ea.x * w20[3] + ea.y * w21[3] + ea.z * w22[3]);
            }
        }
        if (!(a0 == a0)) { a0 = 777.f; badA++; }
        if (!(a1 == a1)) { a1 = 777.f; badA++; }
        if (!(a2 == a2)) { a2 = 777.f; badA++; }
        if (!(a3 == a3)) { a3 = 777.f; badA++; }
        float4 o; o.x = a0; o.y = a1; o.z = a2; o.w = a3;
        *(float4*)(aggL + t * LDA + lane * 4) = o;
    }
    if (badA) atomicAdd(&diag[layer == 0 ? 1 : 3], badA);

    // ---- phase 2: GEMM over K=512, A = [h | agg] ----
    // thread tile: 4 rows x 8 cols
    int g_m = tid & 7, g_c = tid >> 3;
    int m0 = n0 + g_m * 4;
    int c0 = g_c * 8;

    float acc[4][8];
#pragma unroll
    for (int i = 0; i < 4; ++i)
#pragma unroll
        for (int j = 0; j < 8; ++j) acc[i][j] = 0.f;

    for (int kb = 0; kb < 32; ++kb) {     // 16 k per chunk
        __syncthreads();
#pragma unroll
        for (int jj = 0; jj < 16; ++jj) Wl[jj * 256 + tid] = W[(size_t)(kb * 16 + jj) * HID + tid];
        __syncthreads();

#pragma unroll
        for (int kq = 0; kq < 4; ++kq) {
            int k = kb * 16 + kq * 4;
            float a[4][4];
            if (kb < 16) {
#pragma unroll
                for (int i = 0; i < 4; ++i) {
                    int m = m0 + i;
                    int mc = m < M ? m : M - 1;
                    float4 av = *(const float4*)(hin + (size_t)mc * HID + k);
                    a[i][0] = av.x; a[i][1] = av.y; a[i][2] = av.z; a[i][3] = av.w;
                }
            } else {
#pragma unroll
                for (int i = 0; i < 4; ++i) {
                    float4 av = *(const float4*)(aggL + (g_m * 4 + i) * LDA + (k - 256));
                    a[i][0] = av.x; a[i][1] = av.y; a[i][2] = av.z; a[i][3] = av.w;
                }
            }
#pragma unroll
            for (int t4 = 0; t4 < 4; ++t4) {
                const float* wrow = Wl + (kq * 4 + t4) * 256 + c0;
                float w0 = wrow[0], w1 = wrow[1], w2 = wrow[2], w3 = wrow[3];
                float w4 = wrow[4], w5 = wrow[5], w6 = wrow[6], w7 = wrow[7];
#pragma unroll
                for (int i = 0; i < 4; ++i) {
                    float av = a[i][t4];
                    acc[i][0] += av * w0; acc[i][1] += av * w1;
                    acc[i][2] += av * w2; acc[i][3] += av * w3;
                    acc[i][4] += av * w4; acc[i][5] += av * w5;
                    acc[i][6] += av * w6; acc[i][7] += av * w7;
                }
            }
        }
    }

    // ---- epilogue: bias + ReLU + store + BN partial stats ----
    float cs[8], cq[8];
#pragma unroll
    for (int j = 0; j < 8; ++j) { cs[j] = 0.f; cq[j] = 0.f; }
    int badY = 0;
#pragma unroll
    for (int i = 0; i < 4; ++i) {
        int m = m0 + i;
        if (m < M) {
#pragma unroll
            for (int j = 0; j < 8; ++j) {
                int c = c0 + j;
                float v = acc[i][j] + bias[c];
                if (!(v == v)) { v = 777.f; badY++; }
                v = v > 0.f ? v : 0.f;
                hdst[(size_t)m * HID + c] = v;
                cs[j] += v;
                cq[j] += v * v;
            }
        }
    }
    if (badY) atomicAdd(&diag[layer == 0 ? 2 : 4], badY);
#pragma unroll
    for (int j = 0; j < 8; ++j) {
        atomicAdd(&lsum[c0 + j], cs[j]);
        atomicAdd(&lsq[c0 + j], cq[j]);
    }
    __syncthreads();
    atomicAdd(&colsum[tid], lsum[tid]);
    atomicAdd(&colsumsq[tid], lsq[tid]);
}

__global__ void k_bnscale(const float* colsum, const float* colsumsq,
                          const float* g, const float* b,
                          float* scale, float* shift, int* diag, int M) {
    int c = threadIdx.x;
    float mu = colsum[c] / (float)M;
    float var = colsumsq[c] / (float)M - mu * mu;
    int bad = 0;
    if (!(mu == mu) || !(var == var) || var > 1e30f) { bad = 1; }
    if (var < 0.f) var = 0.f;
    if (bad) atomicAdd(&diag[5], 1);
    float sc = rsqrtf(var + BN_EPS) * g[c];
    scale[c] = sc;
    shift[c] = b[c] - mu * sc;
}

__global__ void k_bnapply(float* h, const float* scale, const float* shift, int total, int relu) {
    int idx = (blockIdx.x * 256 + threadIdx.x) * 4;
    if (idx >= total) return;
    int c = idx & (HID - 1);
    float4 v = *(const float4*)(h + idx);
    float o0 = scale[c + 0] * v.x + shift[c + 0];
    float o1 = scale[c + 1] * v.y + shift[c + 1];
    float o2 = scale[c + 2] * v.z + shift[c + 2];
    float o3 = scale[c + 3] * v.w + shift[c + 3];
    if (relu) {
        o0 = o0 > 0.f ? o0 : 0.f;
        o1 = o1 > 0.f ? o1 : 0.f;
        o2 = o2 > 0.f ? o2 : 0.f;
        o3 = o3 > 0.f ? o3 : 0.f;
    }
    float4 ov; ov.x = o0; ov.y = o1; ov.z = o2; ov.w = o3;
    *(float4*)(h + idx) = ov;
}

// Failure-stage encode: d_out[0] = (1+idx)*2^20 only if some check failed.
// idx = k + 8*(int64 edge_index) + 16*(ws path); k = first failing of
// {0: CSR integrity, 1: agg NaN L0, 2: y NaN L0, 3: agg NaN L1+, 4: y NaN L1+, 5: BN degenerate}
__global__ void k_encode(const int* diag, float* out, int wsUsed) {
    if (threadIdx.x != 0 || blockIdx.x != 0) return;
    int k = -1;
    for (int i = 0; i < 6; ++i) if (diag[i] != 0) { k = i; break; }
    if (k < 0) return;
    int idx = k + (diag[6] != 0 ? 8 : 0) + (wsUsed ? 16 : 0);
    out[0] = (float)(1 + idx) * 1048576.0f;
}

// ---------------- launcher ----------------

extern "C" void kernel_launch(void* const* d_in, const int* in_sizes, int n_in,
                              void* d_out, int out_size, void* d_ws, size_t ws_size,
                              hipStream_t stream) {
    const float* x     = (const float*)d_in[0];
    const int*   ei    = (const int*)d_in[1];
    const float4* eattr = (const float4*)d_in[2];
    const float* mlp_w = (const float*)d_in[3];
    const float* mlp_b = (const float*)d_in[4];
    const float* ew1   = (const float*)d_in[5];
    const float* ew2   = (const float*)d_in[6];
    const float* bn_g  = (const float*)d_in[7];
    const float* bn_b  = (const float*)d_in[8];
    (void)n_in; (void)out_size;

    const int N = in_sizes[0] / HID;   // 50000
    const int E = in_sizes[1] / 2;     // 320000

    // SENTINEL: pure runtime D2D (fully overwritten by layer 0 when healthy).
    hipMemcpyAsync(d_out, d_in[0], (size_t)N * HID * 4, hipMemcpyDeviceToDevice, stream);

    // ---- staging inside d_out (51.2 MB; dead before layer 0 writes it) ----
    char* st = (char*)d_out;
    int*    S_deg    = (int*)   (st + 0);
    float*  S_dinv   = (float*) (st + 204800);
    int*    S_offs   = (int*)   (st + 409600);
    int*    S_cursor = (int*)   (st + 614400);
    int*    S_bsum   = (int*)   (st + 819200);
    int*    S_bscan  = (int*)   (st + 820224);
    int*    S_gflag  = (int*)   (st + 821248);
    int*    S_row    = (int*)   (st + 1048576);     // E*4 -> ends 2,328,576
    float4* S_ea     = (float4*)(st + 2621440);     // E*16 -> ends 7,741,440 < 51.2 MB

    // ---- final homes: workspace if big enough, else input buffers ----
    int* rowArr; float4* eaP; float* dinvF; int* offsF;
    float* colsum; float* colsq; float* scaleF; float* shiftF;
    int* diag; float* hbuf;
    size_t need = 6805248u + (size_t)N * HID * 4u;   // ~58.0 MB
    int wsUsed = (ws_size >= need) ? 1 : 0;
    if (wsUsed) {
        char* w = (char*)d_ws;
        rowArr = (int*)   (w + 0);          // 1,280,000
        eaP    = (float4*)(w + 1280000);    // 5,120,000
        dinvF  = (float*) (w + 6400000);    // 200,000
        offsF  = (int*)   (w + 6600000);    // 200,004
        colsum = (float*) (w + 6800128);
        colsq  = (float*) (w + 6801152);
        scaleF = (float*) (w + 6802176);
        shiftF = (float*) (w + 6803200);
        diag   = (int*)   (w + 6804224);
        hbuf   = (float*) (w + 6805248);    // 51.2 MB
    } else {
        eaP = (float4*)d_in[2];             // eattr buffer: E*16 = 5,120,000 exact
        char* eb = (char*)d_in[1];          // edge_index buffer: >= 2,560,000
        rowArr = (int*)   (eb + 0);
        dinvF  = (float*) (eb + 1280000);
        offsF  = (int*)   (eb + 1480000);
        colsum = (float*) (eb + 1680128);
        colsq  = (float*) (eb + 1681152);
        scaleF = (float*) (eb + 1682176);
        shiftF = (float*) (eb + 1683200);
        diag   = (int*)   (eb + 1684224);
        hbuf   = (float*)d_in[0];           // x dead after layer 0
    }

    int NB  = (N + 255) / 256;    // 196
    int NBE = (E + 255) / 256;
    int NBK = (N + 31) / 32;      // 1563

    // ---- preprocessing (staging reads ei/eattr; final homes written only after k_place) ----
    k_detect<<<1, 256, 0, stream>>>(ei, S_gflag, E);
    k_zero32<<<NB, 256, 0, stream>>>((unsigned int*)S_deg, N);
    k_deg<<<NBE, 256, 0, stream>>>(ei, S_gflag, S_deg, E, N);
    k_dinv<<<NB, 256, 0, stream>>>(S_deg, S_dinv, N);
    k_scan1<<<NB, 256, 0, stream>>>(S_deg, S_offs, S_bsum, N);
    k_scan2<<<1, 256, 0, stream>>>(S_bsum, S_bscan, NB);
    k_scan3<<<NB, 256, 0, stream>>>(S_offs, S_bscan, S_cursor, N, E);
    k_place<<<NBE, 256, 0, stream>>>(ei, S_gflag, eattr, S_cursor, S_row, S_ea, E, N);
    k_move<<<NBE, 256, 0, stream>>>(S_row, S_ea, S_dinv, S_offs,
                                    rowArr, eaP, dinvF, offsF, E, N);
    k_zero32<<<1, 256, 0, stream>>>((unsigned int*)diag, 256);
    k_precheckN<<<NB, 256, 0, stream>>>(offsF, S_cursor, dinvF, S_gflag, diag, N, E);
    k_precheckE<<<NBE, 256, 0, stream>>>(rowArr, diag, E, N);

    // ---- layers ----
    for (int l = 0; l < NLAYERS; ++l) {
        const float* hin = (l == 0) ? x : ((l & 1) ? (const float*)d_out : hbuf);
        float* hdst = (l & 1) ? hbuf : (float*)d_out;

        k_zero32<<<2, 256, 0, stream>>>((unsigned int*)colsum, 512);
        MPNN_79044578115931_kernel<<<NBK, 256, 0, stream>>>(
            hin, offsF, rowArr, eaP, dinvF,
            ew1 + (size_t)l * 128, ew2 + (size_t)l * 384,
            mlp_w + (size_t)l * 512 * HID, mlp_b + (size_t)l * HID, hdst,
            colsum, colsq, diag, l, N);
        k_bnscale<<<1, 256, 0, stream>>>(colsum, colsq,
                                         bn_g + (size_t)l * HID, bn_b + (size_t)l * HID,
                                         scaleF, shiftF, diag, N);
        int relu = (l != NLAYERS - 1) ? 1 : 0;
        k_bnapply<<<(N * HID / 4 + 255) / 256, 256, 0, stream>>>(hdst, scaleF, shiftF, N * HID, relu);
    }

    k_encode<<<1, 64, 0, stream>>>(diag, (float*)d_out, wsUsed);
}

// Round 12
// 1338.564 us; speedup vs baseline: 5.9998x; 5.9998x over previous
//
#include <hip/hip_runtime.h>

typedef short short8 __attribute__((ext_vector_type(8)));
typedef float f32x4 __attribute__((ext_vector_type(4)));
typedef unsigned short u16;

#define HID 256
#define NLAYERS 5
#define BN_EPS 1e-5f

__device__ __forceinline__ float bf2f(u16 u) {
    union { unsigned int i; float f; } v;
    v.i = ((unsigned int)u) << 16;
    return v.f;
}
__device__ __forceinline__ u16 f2bf(float f) {
    union { float f; unsigned int i; } v;
    v.f = f;
    unsigned int r = v.i + 0x7FFFu + ((v.i >> 16) & 1u);   // RNE
    return (u16)(r >> 16);
}
// split fp32 -> (hi, lo) bf16 pair: hi+lo ~ 17-bit mantissa approximation
__device__ __forceinline__ void split_bf(float f, u16& hi, u16& lo) {
    hi = f2bf(f);
    lo = f2bf(f - bf2f(hi));
}

// ---------------- utility ----------------

__global__ __launch_bounds__(256) void k_zero32(unsigned int* p, int n) {
    int i = blockIdx.x * 256 + threadIdx.x;
    if (i < n) p[i] = 0u;
}

// ---------------- graph preprocessing (staged in d_out) ----------------

__global__ __launch_bounds__(256) void k_detect(const int* ei, int* flag, int E) {
    __shared__ int nz;
    if (threadIdx.x == 0) nz = 0;
    __syncthreads();
    int lim = (2 * E < 4096) ? 2 * E : 4096;
    int c = 0;
    for (int i = threadIdx.x; 2 * i + 1 < lim; i += 256) c += (ei[2 * i + 1] != 0);
    atomicAdd(&nz, c);
    __syncthreads();
    if (threadIdx.x == 0) flag[0] = (nz == 0) ? 1 : 0;   // 1 => int64 layout
}

__global__ __launch_bounds__(256) void k_deg(const int* ei, const int* flag, int* deg, int E, int N) {
    int e = blockIdx.x * 256 + threadIdx.x;
    if (e >= E) return;
    int w = flag[0];
    int col = w ? ei[2 * (E + e)] : ei[E + e];
    if ((unsigned)col < (unsigned)N) atomicAdd(&deg[col], 1);
}

__global__ __launch_bounds__(256) void k_dinv(const int* deg, float* dinv, int N) {
    int n = blockIdx.x * 256 + threadIdx.x;
    if (n < N) { int d = deg[n]; dinv[n] = d > 0 ? rsqrtf((float)d) : 0.0f; }
}

__global__ __launch_bounds__(256) void k_scan1(const int* deg, int* offs, int* bsum, int N) {
    __shared__ int s[256];
    int tid = threadIdx.x;
    int i = blockIdx.x * 256 + tid;
    int v = (i < N) ? deg[i] : 0;
    s[tid] = v;
    __syncthreads();
    for (int off = 1; off < 256; off <<= 1) {
        int t = (tid >= off) ? s[tid - off] : 0;
        __syncthreads();
        s[tid] += t;
        __syncthreads();
    }
    if (i < N) offs[i] = s[tid] - v;
    if (tid == 255) bsum[blockIdx.x] = s[tid];
}

__global__ __launch_bounds__(256) void k_scan2(const int* bsum, int* bscan, int NB) {
    __shared__ int s[256];
    int tid = threadIdx.x;
    int v = (tid < NB) ? bsum[tid] : 0;
    s[tid] = v;
    __syncthreads();
    for (int off = 1; off < 256; off <<= 1) {
        int t = (tid >= off) ? s[tid - off] : 0;
        __syncthreads();
        s[tid] += t;
        __syncthreads();
    }
    bscan[tid] = s[tid] - v;
}

__global__ __launch_bounds__(256) void k_scan3(int* offs, const int* bscan, int* cursor, int N, int E) {
    int i = blockIdx.x * 256 + threadIdx.x;
    if (i < N) {
        int o = offs[i] + bscan[blockIdx.x];
        offs[i] = o;
        cursor[i] = o;
    }
    if (i == 0) offs[N] = E;
}

__global__ __launch_bounds__(256) void k_place(const int* ei, const int* flag, const float4* eattr,
                                               int* cursor, int* srow, float4* sea, int E, int N) {
    int e = blockIdx.x * 256 + threadIdx.x;
    if (e >= E) return;
    int w = flag[0];
    int r = w ? ei[2 * e] : ei[e];
    int c = w ? ei[2 * (E + e)] : ei[E + e];
    if ((unsigned)c >= (unsigned)N) return;
    int p = atomicAdd(&cursor[c], 1);
    srow[p] = r;
    sea[p] = eattr[e];
}

__global__ __launch_bounds__(256) void k_move(const int* srow, const float4* sea, const float* sdinv,
                                              const int* soffs, int* rowArr, float4* eaP,
                                              float* dinvF, int* offsF, int E, int N) {
    int i = blockIdx.x * 256 + threadIdx.x;
    if (i < E) { rowArr[i] = srow[i]; eaP[i] = sea[i]; }
    if (i < N) dinvF[i] = sdinv[i];
    if (i <= N) offsF[i] = soffs[i];
}

__global__ __launch_bounds__(256) void k_precheckN(const int* offsF, const int* cursor, const float* dinvF,
                                                   const int* gflag, int* diag, int N, int E) {
    int i = blockIdx.x * 256 + threadIdx.x;
    if (i < N) {
        if (offsF[i + 1] < offsF[i]) atomicOr(&diag[0], 1);
        if (cursor[i] != offsF[i + 1]) atomicOr(&diag[0], 2);
        float d = dinvF[i];
        if (!(d == d) || fabsf(d) > 1e10f) atomicOr(&diag[0], 4);
    }
    if (i == 0) {
        if (offsF[N] != E) atomicOr(&diag[0], 8);
        diag[7] = gflag[0];
    }
}
__global__ __launch_bounds__(256) void k_precheckE(const int* rowArr, int* diag, int E, int N) {
    int p = blockIdx.x * 256 + threadIdx.x;
    if (p < E && (unsigned)rowArr[p] >= (unsigned)N) atomicOr(&diag[0], 16);
}

// ---------------- per-layer: aggregation (one wave per node), split output ----------------
__global__ __launch_bounds__(256) void k_agg(const void* hin_, const u16* hin_lo, int hf32,
                                             const int* offs, const int* rowArr, const float4* eaP,
                                             const float* dinv, const float* ew1, const float* ew2,
                                             u16* agg_hi, u16* agg_lo, int* diag, int M) {
    int lane = threadIdx.x & 63, wave = threadIdx.x >> 6;
    int n = blockIdx.x * 4 + wave;

    float w1v[4] = {0.f, 0.f, 0.f, 0.f};
    float w20[4] = {0.f, 0.f, 0.f, 0.f};
    float w21[4] = {0.f, 0.f, 0.f, 0.f};
    float w22[4] = {0.f, 0.f, 0.f, 0.f};
    if (lane < 32) {
        int c = lane * 4;
#pragma unroll
        for (int j = 0; j < 4; ++j) w1v[j] = ew1[c + j];
    } else {
        int cc = (lane - 32) * 4;
#pragma unroll
        for (int j = 0; j < 4; ++j) {
            w20[j] = ew2[cc + j];
            w21[j] = ew2[128 + cc + j];
            w22[j] = ew2[256 + cc + j];
        }
    }

    if (n >= M) return;
    float dn = dinv[n];
    int s = offs[n], e = offs[n + 1];
    float a0 = 0.f, a1 = 0.f, a2 = 0.f, a3 = 0.f;
    for (int p = s; p < e; ++p) {
        int r = rowArr[p];
        float4 ea = eaP[p];
        float nrm = dn * dinv[r];
        float h0, h1, h2, h3;
        if (hf32) {
            float4 hv = *((const float4*)hin_ + (size_t)r * 64 + lane);
            h0 = hv.x; h1 = hv.y; h2 = hv.z; h3 = hv.w;
        } else {
            ushort4 hh = *((const ushort4*)hin_ + (size_t)r * 64 + lane);
            ushort4 hl = *((const ushort4*)hin_lo + (size_t)r * 64 + lane);
            h0 = bf2f(hh.x) + bf2f(hl.x);
            h1 = bf2f(hh.y) + bf2f(hl.y);
            h2 = bf2f(hh.z) + bf2f(hl.z);
            h3 = bf2f(hh.w) + bf2f(hl.w);
        }
        a0 += nrm * (h0 + ea.w * w1v[0] + ea.x * w20[0] + ea.y * w21[0] + ea.z * w22[0]);
        a1 += nrm * (h1 + ea.w * w1v[1] + ea.x * w20[1] + ea.y * w21[1] + ea.z * w22[1]);
        a2 += nrm * (h2 + ea.w * w1v[2] + ea.x * w20[2] + ea.y * w21[2] + ea.z * w22[2]);
        a3 += nrm * (h3 + ea.w * w1v[3] + ea.x * w20[3] + ea.y * w21[3] + ea.z * w22[3]);
    }
    int bad = 0;
    if (!(a0 == a0)) { a0 = 777.f; bad++; }
    if (!(a1 == a1)) { a1 = 777.f; bad++; }
    if (!(a2 == a2)) { a2 = 777.f; bad++; }
    if (!(a3 == a3)) { a3 = 777.f; bad++; }
    if (bad) atomicAdd(&diag[1], bad);
    ushort4 oh, ol;
    split_bf(a0, oh.x, ol.x);
    split_bf(a1, oh.y, ol.y);
    split_bf(a2, oh.z, ol.z);
    split_bf(a3, oh.w, ol.w);
    *((ushort4*)agg_hi + (size_t)n * 64 + lane) = oh;
    *((ushort4*)agg_lo + (size_t)n * 64 + lane) = ol;
}

// ---------------- per-layer: split-precision MFMA GEMM + bias/ReLU + BN stats ----------------
// y = relu(A·W + bias); A = [h | agg], both as bf16 hi/lo pairs (fp32 x split on the fly at l0).
// acc = Ahi·Whi + Alo·Whi + Ahi·Wlo  (~fp32 quality). Block: 64 rows x 256 cols, 4 waves.
__global__ __launch_bounds__(256) void MPNN_79044578115931_kernel(
        const void* hinA_, const u16* hinA_lo, int hf32,
        const u16* agg_hi, const u16* agg_lo,
        const float* W, const float* bias,
        u16* y_hi, u16* y_lo,
        float* colsum, float* colsumsq, int* diag, int M) {
    __shared__ u16 bhi[8192];          // 16 KB: B hi-frags for current kb
    __shared__ u16 blo[8192];          // 16 KB: B lo-frags
    __shared__ float lsum[256];
    __shared__ float lsq[256];

    int tid = threadIdx.x;
    int lane = tid & 63, wave = tid >> 6;
    int quad = lane >> 4, nl = lane & 15;
    int mBase = blockIdx.x * 64 + wave * 16;
    int rowA = mBase + nl;
    if (rowA >= M) rowA = M - 1;

    lsum[tid] = 0.f;
    lsq[tid] = 0.f;

    f32x4 acc[16];
#pragma unroll
    for (int i = 0; i < 16; ++i) acc[i] = {0.f, 0.f, 0.f, 0.f};

    for (int kb = 0; kb < 16; ++kb) {
        __syncthreads();   // prior-kb B reads complete
        // stage + split B chunk from fp32 W (L2-hot): frag t=(nbg*64+lane), 8 k-elems each
#pragma unroll
        for (int i = 0; i < 4; ++i) {
            int t = tid + i * 256;
            int bl = t & 63;
            int bn = ((t >> 6) << 4) | (bl & 15);
            const float* src = W + (size_t)(kb * 32 + (bl >> 4) * 8) * HID + bn;
            short8 vh, vl;
#pragma unroll
            for (int j = 0; j < 8; ++j) {
                float w = src[(size_t)j * HID];
                u16 h, l;
                split_bf(w, h, l);
                vh[j] = (short)h;
                vl[j] = (short)l;
            }
            *((short8*)bhi + t) = vh;
            *((short8*)blo + t) = vl;
        }
        __syncthreads();

        short8 a_hi, a_lo;
        if (kb < 8) {
            int k0 = kb * 32 + quad * 8;
            if (hf32) {
                const float* hp = (const float*)hinA_ + (size_t)rowA * HID + k0;
#pragma unroll
                for (int j = 0; j < 8; ++j) {
                    u16 h, l;
                    split_bf(hp[j], h, l);
                    a_hi[j] = (short)h;
                    a_lo[j] = (short)l;
                }
            } else {
                a_hi = *(const short8*)((const u16*)hinA_ + (size_t)rowA * HID + k0);
                a_lo = *(const short8*)(hinA_lo + (size_t)rowA * HID + k0);
            }
        } else {
            int k0 = (kb - 8) * 32 + quad * 8;
            a_hi = *(const short8*)(agg_hi + (size_t)rowA * HID + k0);
            a_lo = *(const short8*)(agg_lo + (size_t)rowA * HID + k0);
        }

#pragma unroll
        for (int nbg = 0; nbg < 16; ++nbg) {
            short8 bh = *((const short8*)bhi + nbg * 64 + lane);
            short8 bl = *((const short8*)blo + nbg * 64 + lane);
            acc[nbg] = __builtin_amdgcn_mfma_f32_16x16x32_bf16(a_hi, bh, acc[nbg], 0, 0, 0);
            acc[nbg] = __builtin_amdgcn_mfma_f32_16x16x32_bf16(a_lo, bh, acc[nbg], 0, 0, 0);
            acc[nbg] = __builtin_amdgcn_mfma_f32_16x16x32_bf16(a_hi, bl, acc[nbg], 0, 0, 0);
        }
    }

    // epilogue: bias + ReLU + split-store + BN partial stats (pre-split fp32)
    int badY = 0;
#pragma unroll
    for (int nbg = 0; nbg < 16; ++nbg) {
        int c = nbg * 16 + nl;
        float bv = bias[c];
        float s = 0.f, q = 0.f;
#pragma unroll
        for (int r = 0; r < 4; ++r) {
            int m = mBase + quad * 4 + r;
            if (m < M) {
                float v = acc[nbg][r] + bv;
                if (!(v == v)) { v = 777.f; badY++; }
                v = v > 0.f ? v : 0.f;
                u16 h, l;
                split_bf(v, h, l);
                y_hi[(size_t)m * HID + c] = h;
                y_lo[(size_t)m * HID + c] = l;
                s += v;
                q += v * v;
            }
        }
        atomicAdd(&lsum[c], s);
        atomicAdd(&lsq[c], q);
    }
    if (badY) atomicAdd(&diag[2], badY);
    __syncthreads();
    atomicAdd(&colsum[tid], lsum[tid]);
    atomicAdd(&colsumsq[tid], lsq[tid]);
}

__global__ __launch_bounds__(256) void k_bnscale(const float* colsum, const float* colsumsq,
                                                 const float* g, const float* b,
                                                 float* scale, float* shift, int* diag, int M) {
    int c = threadIdx.x;
    float mu = colsum[c] / (float)M;
    float var = colsumsq[c] / (float)M - mu * mu;
    if (!(mu == mu) || !(var == var) || var > 1e30f) atomicAdd(&diag[3], 1);
    if (var < 0.f) var = 0.f;
    float sc = rsqrtf(var + BN_EPS) * g[c];
    scale[c] = sc;
    shift[c] = b[c] - mu * sc;
}

// BN apply: non-final = in-place on hi/lo planes (+ReLU); final = write fp32 to outf.
__global__ __launch_bounds__(256) void k_bnapply(u16* y_hi, u16* y_lo,
                                                 const float* scale, const float* shift,
                                                 float* outf, int finalL, int relu, int total) {
    int q4 = blockIdx.x * 256 + threadIdx.x;
    int idx = q4 * 4;
    if (idx >= total) return;
    int c = idx & (HID - 1);
    ushort4 vh = *((const ushort4*)y_hi + q4);
    ushort4 vl = *((const ushort4*)y_lo + q4);
    float o0 = scale[c + 0] * (bf2f(vh.x) + bf2f(vl.x)) + shift[c + 0];
    float o1 = scale[c + 1] * (bf2f(vh.y) + bf2f(vl.y)) + shift[c + 1];
    float o2 = scale[c + 2] * (bf2f(vh.z) + bf2f(vl.z)) + shift[c + 2];
    float o3 = scale[c + 3] * (bf2f(vh.w) + bf2f(vl.w)) + shift[c + 3];
    if (relu) {
        o0 = o0 > 0.f ? o0 : 0.f;
        o1 = o1 > 0.f ? o1 : 0.f;
        o2 = o2 > 0.f ? o2 : 0.f;
        o3 = o3 > 0.f ? o3 : 0.f;
    }
    if (finalL) {
        float4 ov; ov.x = o0; ov.y = o1; ov.z = o2; ov.w = o3;
        *((float4*)outf + q4) = ov;
    } else {
        ushort4 oh, ol;
        split_bf(o0, oh.x, ol.x);
        split_bf(o1, oh.y, ol.y);
        split_bf(o2, oh.z, ol.z);
        split_bf(o3, oh.w, ol.w);
        *((ushort4*)y_hi + q4) = oh;
        *((ushort4*)y_lo + q4) = ol;
    }
}

// d_out[0] = (1+k+8*int64)*2^20 only if a check failed.
__global__ void k_encode(const int* diag, float* out) {
    if (threadIdx.x != 0 || blockIdx.x != 0) return;
    int k = -1;
    for (int i = 0; i < 4; ++i) if (diag[i] != 0) { k = i; break; }
    if (k < 0) return;
    out[0] = (float)(1 + k + (diag[7] != 0 ? 8 : 0)) * 1048576.0f;
}

// ---------------- launcher (zero workspace dependency) ----------------

extern "C" void kernel_launch(void* const* d_in, const int* in_sizes, int n_in,
                              void* d_out, int out_size, void* d_ws, size_t ws_size,
                              hipStream_t stream) {
    const float*  x     = (const float*)d_in[0];
    const int*    ei    = (const int*)d_in[1];
    const float4* eattr = (const float4*)d_in[2];
    const float*  mlp_w = (const float*)d_in[3];
    const float*  mlp_b = (const float*)d_in[4];
    const float*  ew1   = (const float*)d_in[5];
    const float*  ew2   = (const float*)d_in[6];
    const float*  bn_g  = (const float*)d_in[7];
    const float*  bn_b  = (const float*)d_in[8];
    (void)n_in; (void)out_size; (void)d_ws; (void)ws_size;

    const int N = in_sizes[0] / HID;   // 50000
    const int E = in_sizes[1] / 2;     // 320000
    const size_t P = (size_t)N * HID;  // plane elements

    // ---- CSR staging inside d_out (dead before layer 0 writes d_out) ----
    char* st = (char*)d_out;
    int*    S_deg    = (int*)   (st + 0);
    float*  S_dinv   = (float*) (st + 204800);
    int*    S_offs   = (int*)   (st + 409600);
    int*    S_cursor = (int*)   (st + 614400);
    int*    S_bsum   = (int*)   (st + 819200);
    int*    S_bscan  = (int*)   (st + 820224);
    int*    S_gflag  = (int*)   (st + 821248);
    int*    S_row    = (int*)   (st + 1048576);
    float4* S_ea     = (float4*)(st + 2621440);   // ends 7,741,440 < 51.2 MB

    // ---- final small homes: edge_index buffer (2.56 MB) + eattr buffer (5.12 MB) ----
    char* eb = (char*)d_in[1];
    int*   rowArr = (int*)  (eb + 0);          // 1,280,000
    float* dinvF  = (float*)(eb + 1280000);    // 200,000
    int*   offsF  = (int*)  (eb + 1480000);    // 200,004
    float* colsum = (float*)(eb + 1680128);
    float* colsq  = (float*)(eb + 1681152);
    float* scaleF = (float*)(eb + 1682176);
    float* shiftF = (float*)(eb + 1683200);
    int*   diag   = (int*)  (eb + 1684224);    // ends 1,685,248 <= 2,560,000
    float4* eaP   = (float4*)d_in[2];          // 5,120,000 exact (overwritten via staging)

    // ---- h slots as bf16 hi/lo planes (each slot = 51.2 MB = 2 planes) ----
    u16* sX_hi = (u16*)d_in[0];          // x buffer (x consumed during layer 0)
    u16* sX_lo = sX_hi + P;
    u16* sD_hi = (u16*)d_out;
    u16* sD_lo = sD_hi + P;

    int NB  = (N + 255) / 256;
    int NBE = (E + 255) / 256;
    int NBG = (N + 63) / 64;      // 782 GEMM blocks
    int NBA = (N + 3) / 4;        // 12500 agg blocks (one wave per node)
    int NBQ = (int)((P / 4 + 255) / 256);

    // ---- preprocessing ----
    k_detect<<<1, 256, 0, stream>>>(ei, S_gflag, E);
    k_zero32<<<NB, 256, 0, stream>>>((unsigned int*)S_deg, N);
    k_deg<<<NBE, 256, 0, stream>>>(ei, S_gflag, S_deg, E, N);
    k_dinv<<<NB, 256, 0, stream>>>(S_deg, S_dinv, N);
    k_scan1<<<NB, 256, 0, stream>>>(S_deg, S_offs, S_bsum, N);
    k_scan2<<<1, 256, 0, stream>>>(S_bsum, S_bscan, NB);
    k_scan3<<<NB, 256, 0, stream>>>(S_offs, S_bscan, S_cursor, N, E);
    k_place<<<NBE, 256, 0, stream>>>(ei, S_gflag, eattr, S_cursor, S_row, S_ea, E, N);
    k_zero32<<<1, 256, 0, stream>>>((unsigned int*)(st + 821252), 64);   // pad
    k_move<<<NBE, 256, 0, stream>>>(S_row, S_ea, S_dinv, S_offs, rowArr, eaP, dinvF, offsF, E, N);
    k_zero32<<<1, 256, 0, stream>>>((unsigned int*)diag, 256);
    k_precheckN<<<NB, 256, 0, stream>>>(offsF, S_cursor, dinvF, S_gflag, diag, N, E);
    k_precheckE<<<NBE, 256, 0, stream>>>(rowArr, diag, E, N);

    // ---- layers: even l -> dst = D(d_out), odd l -> dst = X; agg planes live in dst ----
    for (int l = 0; l < NLAYERS; ++l) {
        int even = (l % 2 == 0);
        u16* dst_hi = even ? sD_hi : sX_hi;
        u16* dst_lo = even ? sD_lo : sX_lo;
        const void* hinA; const u16* hin_lo; int hf32;
        if (l == 0) { hinA = (const void*)x; hin_lo = 0; hf32 = 1; }
        else if (even) { hinA = (const void*)sX_hi; hin_lo = sX_lo; hf32 = 0; }
        else { hinA = (const void*)sD_hi; hin_lo = sD_lo; hf32 = 0; }

        k_agg<<<NBA, 256, 0, stream>>>(hinA, hin_lo, hf32, offsF, rowArr, eaP, dinvF,
                                       ew1 + (size_t)l * 128, ew2 + (size_t)l * 384,
                                       dst_hi, dst_lo, diag, N);
        k_zero32<<<2, 256, 0, stream>>>((unsigned int*)colsum, 512);
        MPNN_79044578115931_kernel<<<NBG, 256, 0, stream>>>(
            hinA, hin_lo, hf32, dst_hi, dst_lo,
            mlp_w + (size_t)l * 512 * HID, mlp_b + (size_t)l * HID,
            dst_hi, dst_lo, colsum, colsq, diag, N);
        k_bnscale<<<1, 256, 0, stream>>>(colsum, colsq,
                                         bn_g + (size_t)l * HID, bn_b + (size_t)l * HID,
                                         scaleF, shiftF, diag, N);
        int finalL = (l == NLAYERS - 1) ? 1 : 0;
        int relu = finalL ? 0 : 1;
        // final: expand planes (in d_out) -> fp32 into X buffer, then copy back to d_out
        k_bnapply<<<NBQ, 256, 0, stream>>>(dst_hi, dst_lo, scaleF, shiftF,
                                           (float*)d_in[0], finalL, relu, (int)P);
    }

    hipMemcpyAsync(d_out, d_in[0], P * 4, hipMemcpyDeviceToDevice, stream);
    k_encode<<<1, 64, 0, stream>>>(diag, (float*)d_out);
}

// Round 13
// 1273.603 us; speedup vs baseline: 6.3058x; 1.0510x over previous
//
#include <hip/hip_runtime.h>

typedef short short8 __attribute__((ext_vector_type(8)));
typedef float f32x4 __attribute__((ext_vector_type(4)));
typedef unsigned short u16;

#define HID 256
#define NLAYERS 5
#define BN_EPS 1e-5f

__device__ __forceinline__ float bf2f(u16 u) {
    union { unsigned int i; float f; } v;
    v.i = ((unsigned int)u) << 16;
    return v.f;
}
__device__ __forceinline__ u16 f2bf(float f) {
    union { float f; unsigned int i; } v;
    v.f = f;
    unsigned int r = v.i + 0x7FFFu + ((v.i >> 16) & 1u);   // RNE
    return (u16)(r >> 16);
}
// split fp32 -> (hi, lo) bf16 pair: hi+lo ~ 17-bit mantissa approximation
__device__ __forceinline__ void split_bf(float f, u16& hi, u16& lo) {
    hi = f2bf(f);
    lo = f2bf(f - bf2f(hi));
}

// ---------------- utility ----------------

__global__ __launch_bounds__(256) void k_zero32(unsigned int* p, int n) {
    int i = blockIdx.x * 256 + threadIdx.x;
    if (i < n) p[i] = 0u;
}

// ---------------- graph preprocessing (staged in d_out) ----------------

__global__ __launch_bounds__(256) void k_detect(const int* ei, int* flag, int E) {
    __shared__ int nz;
    if (threadIdx.x == 0) nz = 0;
    __syncthreads();
    int lim = (2 * E < 4096) ? 2 * E : 4096;
    int c = 0;
    for (int i = threadIdx.x; 2 * i + 1 < lim; i += 256) c += (ei[2 * i + 1] != 0);
    atomicAdd(&nz, c);
    __syncthreads();
    if (threadIdx.x == 0) flag[0] = (nz == 0) ? 1 : 0;   // 1 => int64 layout
}

__global__ __launch_bounds__(256) void k_deg(const int* ei, const int* flag, int* deg, int E, int N) {
    int e = blockIdx.x * 256 + threadIdx.x;
    if (e >= E) return;
    int w = flag[0];
    int col = w ? ei[2 * (E + e)] : ei[E + e];
    if ((unsigned)col < (unsigned)N) atomicAdd(&deg[col], 1);
}

__global__ __launch_bounds__(256) void k_dinv(const int* deg, float* dinv, int N) {
    int n = blockIdx.x * 256 + threadIdx.x;
    if (n < N) { int d = deg[n]; dinv[n] = d > 0 ? rsqrtf((float)d) : 0.0f; }
}

__global__ __launch_bounds__(256) void k_scan1(const int* deg, int* offs, int* bsum, int N) {
    __shared__ int s[256];
    int tid = threadIdx.x;
    int i = blockIdx.x * 256 + tid;
    int v = (i < N) ? deg[i] : 0;
    s[tid] = v;
    __syncthreads();
    for (int off = 1; off < 256; off <<= 1) {
        int t = (tid >= off) ? s[tid - off] : 0;
        __syncthreads();
        s[tid] += t;
        __syncthreads();
    }
    if (i < N) offs[i] = s[tid] - v;
    if (tid == 255) bsum[blockIdx.x] = s[tid];
}

__global__ __launch_bounds__(256) void k_scan2(const int* bsum, int* bscan, int NB) {
    __shared__ int s[256];
    int tid = threadIdx.x;
    int v = (tid < NB) ? bsum[tid] : 0;
    s[tid] = v;
    __syncthreads();
    for (int off = 1; off < 256; off <<= 1) {
        int t = (tid >= off) ? s[tid - off] : 0;
        __syncthreads();
        s[tid] += t;
        __syncthreads();
    }
    bscan[tid] = s[tid] - v;
}

__global__ __launch_bounds__(256) void k_scan3(int* offs, const int* bscan, int* cursor, int N, int E) {
    int i = blockIdx.x * 256 + threadIdx.x;
    if (i < N) {
        int o = offs[i] + bscan[blockIdx.x];
        offs[i] = o;
        cursor[i] = o;
    }
    if (i == 0) offs[N] = E;
}

__global__ __launch_bounds__(256) void k_place(const int* ei, const int* flag, const float4* eattr,
                                               int* cursor, int* srow, float4* sea, int E, int N) {
    int e = blockIdx.x * 256 + threadIdx.x;
    if (e >= E) return;
    int w = flag[0];
    int r = w ? ei[2 * e] : ei[e];
    int c = w ? ei[2 * (E + e)] : ei[E + e];
    if ((unsigned)c >= (unsigned)N) return;
    int p = atomicAdd(&cursor[c], 1);
    srow[p] = r;
    sea[p] = eattr[e];
}

__global__ __launch_bounds__(256) void k_move(const int* srow, const float4* sea, const float* sdinv,
                                              const int* soffs, int* rowArr, float4* eaP,
                                              float* dinvF, int* offsF, int E, int N) {
    int i = blockIdx.x * 256 + threadIdx.x;
    if (i < E) { rowArr[i] = srow[i]; eaP[i] = sea[i]; }
    if (i < N) dinvF[i] = sdinv[i];
    if (i <= N) offsF[i] = soffs[i];
}

__global__ __launch_bounds__(256) void k_precheckN(const int* offsF, const int* cursor, const float* dinvF,
                                                   const int* gflag, int* diag, int N, int E) {
    int i = blockIdx.x * 256 + threadIdx.x;
    if (i < N) {
        if (offsF[i + 1] < offsF[i]) atomicOr(&diag[0], 1);
        if (cursor[i] != offsF[i + 1]) atomicOr(&diag[0], 2);
        float d = dinvF[i];
        if (!(d == d) || fabsf(d) > 1e10f) atomicOr(&diag[0], 4);
    }
    if (i == 0) {
        if (offsF[N] != E) atomicOr(&diag[0], 8);
        diag[7] = gflag[0];
    }
}
__global__ __launch_bounds__(256) void k_precheckE(const int* rowArr, int* diag, int E, int N) {
    int p = blockIdx.x * 256 + threadIdx.x;
    if (p < E && (unsigned)rowArr[p] >= (unsigned)N) atomicOr(&diag[0], 16);
}

// Per-layer: split W (fp32 512x256 row-major) into bf16 hi/lo planes in MFMA
// B-fragment order, kb-major: frag t = kb*1024 + nbg*64 + lane holds
// W[kb*32 + (lane>>4)*8 + j][nbg*16 + (lane&15)], j=0..7.
// Block 0 also zeroes the BN stats accumulators (512 floats at colsum).
__global__ __launch_bounds__(256) void k_wsplit(const float* W, u16* wpH, u16* wpL, float* colsum) {
    if (blockIdx.x == 0) {
        colsum[threadIdx.x] = 0.f;
        colsum[256 + threadIdx.x] = 0.f;
    }
    int t = blockIdx.x * 256 + threadIdx.x;   // 64 blocks -> 16384 frags
    int lane = t & 63;
    int nbg = (t >> 6) & 15;
    int kb = t >> 10;
    int quad = lane >> 4, nl = lane & 15;
    const float* src = W + (size_t)(kb * 32 + quad * 8) * HID + nbg * 16 + nl;
    short8 vh, vl;
#pragma unroll
    for (int j = 0; j < 8; ++j) {
        u16 h, l;
        split_bf(src[(size_t)j * HID], h, l);
        vh[j] = (short)h;
        vl[j] = (short)l;
    }
    *((short8*)wpH + t) = vh;
    *((short8*)wpL + t) = vl;
}

// ---------------- per-layer: aggregation (one wave per node), split output ----------------
__global__ __launch_bounds__(256) void k_agg(const void* hin_, const u16* hin_lo, int hf32,
                                             const int* offs, const int* rowArr, const float4* eaP,
                                             const float* dinv, const float* ew1, const float* ew2,
                                             u16* agg_hi, u16* agg_lo, int* diag, int M) {
    int lane = threadIdx.x & 63, wave = threadIdx.x >> 6;
    int n = blockIdx.x * 4 + wave;

    float w1v[4] = {0.f, 0.f, 0.f, 0.f};
    float w20[4] = {0.f, 0.f, 0.f, 0.f};
    float w21[4] = {0.f, 0.f, 0.f, 0.f};
    float w22[4] = {0.f, 0.f, 0.f, 0.f};
    if (lane < 32) {
        int c = lane * 4;
#pragma unroll
        for (int j = 0; j < 4; ++j) w1v[j] = ew1[c + j];
    } else {
        int cc = (lane - 32) * 4;
#pragma unroll
        for (int j = 0; j < 4; ++j) {
            w20[j] = ew2[cc + j];
            w21[j] = ew2[128 + cc + j];
            w22[j] = ew2[256 + cc + j];
        }
    }

    if (n >= M) return;
    float dn = dinv[n];
    int s = offs[n], e = offs[n + 1];
    float a0 = 0.f, a1 = 0.f, a2 = 0.f, a3 = 0.f;
    for (int p = s; p < e; ++p) {
        int r = rowArr[p];
        float4 ea = eaP[p];
        float nrm = dn * dinv[r];
        float h0, h1, h2, h3;
        if (hf32) {
            float4 hv = *((const float4*)hin_ + (size_t)r * 64 + lane);
            h0 = hv.x; h1 = hv.y; h2 = hv.z; h3 = hv.w;
        } else {
            ushort4 hh = *((const ushort4*)hin_ + (size_t)r * 64 + lane);
            ushort4 hl = *((const ushort4*)hin_lo + (size_t)r * 64 + lane);
            h0 = bf2f(hh.x) + bf2f(hl.x);
            h1 = bf2f(hh.y) + bf2f(hl.y);
            h2 = bf2f(hh.z) + bf2f(hl.z);
            h3 = bf2f(hh.w) + bf2f(hl.w);
        }
        a0 += nrm * (h0 + ea.w * w1v[0] + ea.x * w20[0] + ea.y * w21[0] + ea.z * w22[0]);
        a1 += nrm * (h1 + ea.w * w1v[1] + ea.x * w20[1] + ea.y * w21[1] + ea.z * w22[1]);
        a2 += nrm * (h2 + ea.w * w1v[2] + ea.x * w20[2] + ea.y * w21[2] + ea.z * w22[2]);
        a3 += nrm * (h3 + ea.w * w1v[3] + ea.x * w20[3] + ea.y * w21[3] + ea.z * w22[3]);
    }
    int bad = 0;
    if (!(a0 == a0)) { a0 = 777.f; bad++; }
    if (!(a1 == a1)) { a1 = 777.f; bad++; }
    if (!(a2 == a2)) { a2 = 777.f; bad++; }
    if (!(a3 == a3)) { a3 = 777.f; bad++; }
    if (bad) atomicAdd(&diag[1], bad);
    ushort4 oh, ol;
    split_bf(a0, oh.x, ol.x);
    split_bf(a1, oh.y, ol.y);
    split_bf(a2, oh.z, ol.z);
    split_bf(a3, oh.w, ol.w);
    *((ushort4*)agg_hi + (size_t)n * 64 + lane) = oh;
    *((ushort4*)agg_lo + (size_t)n * 64 + lane) = ol;
}

// ---------------- per-layer: split-precision MFMA GEMM + bias/ReLU + BN stats ----------------
// y = relu(A·W + bias); A = [h | agg] as bf16 hi/lo pairs (fp32 x split on the fly at l0).
// acc = Ahi·Whi + Alo·Whi + Ahi·Wlo. B-frags read directly from L2-hot pre-split
// wperm planes (no LDS staging, no K-loop barriers). Block: 64 rows x 256 cols, 4 waves.
__global__ __launch_bounds__(256) void MPNN_79044578115931_kernel(
        const void* hinA_, const u16* hinA_lo, int hf32,
        const u16* agg_hi, const u16* agg_lo,
        const u16* wpH, const u16* wpL, const float* bias,
        u16* y_hi, u16* y_lo,
        float* colsum, float* colsumsq, int* diag, int M) {
    __shared__ float lsum[256];
    __shared__ float lsq[256];

    int tid = threadIdx.x;
    int lane = tid & 63, wave = tid >> 6;
    int quad = lane >> 4, nl = lane & 15;
    int mBase = blockIdx.x * 64 + wave * 16;
    int rowA = mBase + nl;
    if (rowA >= M) rowA = M - 1;

    lsum[tid] = 0.f;
    lsq[tid] = 0.f;

    f32x4 acc[16];
#pragma unroll
    for (int i = 0; i < 16; ++i) acc[i] = {0.f, 0.f, 0.f, 0.f};

    for (int kb = 0; kb < 16; ++kb) {
        short8 a_hi, a_lo;
        if (kb < 8) {
            int k0 = kb * 32 + quad * 8;
            if (hf32) {
                const float* hp = (const float*)hinA_ + (size_t)rowA * HID + k0;
#pragma unroll
                for (int j = 0; j < 8; ++j) {
                    u16 h, l;
                    split_bf(hp[j], h, l);
                    a_hi[j] = (short)h;
                    a_lo[j] = (short)l;
                }
            } else {
                a_hi = *(const short8*)((const u16*)hinA_ + (size_t)rowA * HID + k0);
                a_lo = *(const short8*)(hinA_lo + (size_t)rowA * HID + k0);
            }
        } else {
            int k0 = (kb - 8) * 32 + quad * 8;
            a_hi = *(const short8*)(agg_hi + (size_t)rowA * HID + k0);
            a_lo = *(const short8*)(agg_lo + (size_t)rowA * HID + k0);
        }

        const short8* bh0 = (const short8*)wpH + kb * 1024 + lane;
        const short8* bl0 = (const short8*)wpL + kb * 1024 + lane;
#pragma unroll
        for (int nbg = 0; nbg < 16; ++nbg) {
            short8 bh = bh0[nbg * 64];
            short8 bl = bl0[nbg * 64];
            acc[nbg] = __builtin_amdgcn_mfma_f32_16x16x32_bf16(a_hi, bh, acc[nbg], 0, 0, 0);
            acc[nbg] = __builtin_amdgcn_mfma_f32_16x16x32_bf16(a_lo, bh, acc[nbg], 0, 0, 0);
            acc[nbg] = __builtin_amdgcn_mfma_f32_16x16x32_bf16(a_hi, bl, acc[nbg], 0, 0, 0);
        }
    }

    __syncthreads();   // lsum/lsq init visible to all before atomics

    // epilogue: bias + ReLU + split-store + BN partial stats (pre-split fp32)
    int badY = 0;
#pragma unroll
    for (int nbg = 0; nbg < 16; ++nbg) {
        int c = nbg * 16 + nl;
        float bv = bias[c];
        float s = 0.f, q = 0.f;
#pragma unroll
        for (int r = 0; r < 4; ++r) {
            int m = mBase + quad * 4 + r;
            if (m < M) {
                float v = acc[nbg][r] + bv;
                if (!(v == v)) { v = 777.f; badY++; }
                v = v > 0.f ? v : 0.f;
                u16 h, l;
                split_bf(v, h, l);
                y_hi[(size_t)m * HID + c] = h;
                y_lo[(size_t)m * HID + c] = l;
                s += v;
                q += v * v;
            }
        }
        atomicAdd(&lsum[c], s);
        atomicAdd(&lsq[c], q);
    }
    if (badY) atomicAdd(&diag[2], badY);
    __syncthreads();
    atomicAdd(&colsum[tid], lsum[tid]);
    atomicAdd(&colsumsq[tid], lsq[tid]);
}

__global__ __launch_bounds__(256) void k_bnscale(const float* colsum, const float* colsumsq,
                                                 const float* g, const float* b,
                                                 float* scale, float* shift, int* diag, int M) {
    int c = threadIdx.x;
    float mu = colsum[c] / (float)M;
    float var = colsumsq[c] / (float)M - mu * mu;
    if (!(mu == mu) || !(var == var) || var > 1e30f) atomicAdd(&diag[3], 1);
    if (var < 0.f) var = 0.f;
    float sc = rsqrtf(var + BN_EPS) * g[c];
    scale[c] = sc;
    shift[c] = b[c] - mu * sc;
}

// BN apply: non-final = in-place on hi/lo planes (+ReLU); final = write fp32 to outf.
__global__ __launch_bounds__(256) void k_bnapply(u16* y_hi, u16* y_lo,
                                                 const float* scale, const float* shift,
                                                 float* outf, int finalL, int relu, int total) {
    int q4 = blockIdx.x * 256 + threadIdx.x;
    int idx = q4 * 4;
    if (idx >= total) return;
    int c = idx & (HID - 1);
    ushort4 vh = *((const ushort4*)y_hi + q4);
    ushort4 vl = *((const ushort4*)y_lo + q4);
    float o0 = scale[c + 0] * (bf2f(vh.x) + bf2f(vl.x)) + shift[c + 0];
    float o1 = scale[c + 1] * (bf2f(vh.y) + bf2f(vl.y)) + shift[c + 1];
    float o2 = scale[c + 2] * (bf2f(vh.z) + bf2f(vl.z)) + shift[c + 2];
    float o3 = scale[c + 3] * (bf2f(vh.w) + bf2f(vl.w)) + shift[c + 3];
    if (relu) {
        o0 = o0 > 0.f ? o0 : 0.f;
        o1 = o1 > 0.f ? o1 : 0.f;
        o2 = o2 > 0.f ? o2 : 0.f;
        o3 = o3 > 0.f ? o3 : 0.f;
    }
    if (finalL) {
        float4 ov; ov.x = o0; ov.y = o1; ov.z = o2; ov.w = o3;
        *((float4*)outf + q4) = ov;
    } else {
        ushort4 oh, ol;
        split_bf(o0, oh.x, ol.x);
        split_bf(o1, oh.y, ol.y);
        split_bf(o2, oh.z, ol.z);
        split_bf(o3, oh.w, ol.w);
        *((ushort4*)y_hi + q4) = oh;
        *((ushort4*)y_lo + q4) = ol;
    }
}

// d_out[0] = (1+k+8*int64)*2^20 only if a check failed.
__global__ void k_encode(const int* diag, float* out) {
    if (threadIdx.x != 0 || blockIdx.x != 0) return;
    int k = -1;
    for (int i = 0; i < 4; ++i) if (diag[i] != 0) { k = i; break; }
    if (k < 0) return;
    out[0] = (float)(1 + k + (diag[7] != 0 ? 8 : 0)) * 1048576.0f;
}

// ---------------- launcher (zero workspace dependency) ----------------

extern "C" void kernel_launch(void* const* d_in, const int* in_sizes, int n_in,
                              void* d_out, int out_size, void* d_ws, size_t ws_size,
                              hipStream_t stream) {
    const float*  x     = (const float*)d_in[0];
    const int*    ei    = (const int*)d_in[1];
    const float4* eattr = (const float4*)d_in[2];
    const float*  mlp_w = (const float*)d_in[3];
    const float*  mlp_b = (const float*)d_in[4];
    const float*  ew1   = (const float*)d_in[5];
    const float*  ew2   = (const float*)d_in[6];
    const float*  bn_g  = (const float*)d_in[7];
    const float*  bn_b  = (const float*)d_in[8];
    (void)n_in; (void)out_size; (void)d_ws; (void)ws_size;

    const int N = in_sizes[0] / HID;   // 50000
    const int E = in_sizes[1] / 2;     // 320000
    const size_t P = (size_t)N * HID;  // plane elements

    // ---- CSR staging inside d_out (dead before layer 0 writes d_out) ----
    char* st = (char*)d_out;
    int*    S_deg    = (int*)   (st + 0);
    float*  S_dinv   = (float*) (st + 204800);
    int*    S_offs   = (int*)   (st + 409600);
    int*    S_cursor = (int*)   (st + 614400);
    int*    S_bsum   = (int*)   (st + 819200);
    int*    S_bscan  = (int*)   (st + 820224);
    int*    S_gflag  = (int*)   (st + 821248);
    int*    S_row    = (int*)   (st + 1048576);
    float4* S_ea     = (float4*)(st + 2621440);   // ends 7,741,440 < 51.2 MB

    // ---- small homes in edge_index buffer (>=2.56 MB); eattr buffer holds eaP ----
    char* eb = (char*)d_in[1];
    int*   rowArr = (int*)  (eb + 0);          // 1,280,000
    float* dinvF  = (float*)(eb + 1280000);    // 200,000
    int*   offsF  = (int*)  (eb + 1480000);    // 200,004
    float* colsum = (float*)(eb + 1680128);
    float* colsq  = (float*)(eb + 1681152);
    float* scaleF = (float*)(eb + 1682176);
    float* shiftF = (float*)(eb + 1683200);
    int*   diag   = (int*)  (eb + 1684224);    // 1 KB
    u16*   wpH    = (u16*)  (eb + 1685504);    // 256 KB -> ends 1,947,648
    u16*   wpL    = (u16*)  (eb + 1947648);    // 256 KB -> ends 2,209,792 <= 2,560,000
    float4* eaP   = (float4*)d_in[2];          // 5,120,000 exact

    // ---- h slots as bf16 hi/lo planes (each slot = 2 planes = 51.2 MB) ----
    u16* sX_hi = (u16*)d_in[0];          // x buffer (x consumed during layer 0)
    u16* sX_lo = sX_hi + P;
    u16* sD_hi = (u16*)d_out;
    u16* sD_lo = sD_hi + P;

    int NB  = (N + 255) / 256;
    int NBE = (E + 255) / 256;
    int NBG = (N + 63) / 64;      // 782 GEMM blocks
    int NBA = (N + 3) / 4;        // 12500 agg blocks (one wave per node)
    int NBQ = (int)((P / 4 + 255) / 256);

    // ---- preprocessing ----
    k_detect<<<1, 256, 0, stream>>>(ei, S_gflag, E);
    k_zero32<<<NB, 256, 0, stream>>>((unsigned int*)S_deg, N);
    k_deg<<<NBE, 256, 0, stream>>>(ei, S_gflag, S_deg, E, N);
    k_dinv<<<NB, 256, 0, stream>>>(S_deg, S_dinv, N);
    k_scan1<<<NB, 256, 0, stream>>>(S_deg, S_offs, S_bsum, N);
    k_scan2<<<1, 256, 0, stream>>>(S_bsum, S_bscan, NB);
    k_scan3<<<NB, 256, 0, stream>>>(S_offs, S_bscan, S_cursor, N, E);
    k_place<<<NBE, 256, 0, stream>>>(ei, S_gflag, eattr, S_cursor, S_row, S_ea, E, N);
    k_move<<<NBE, 256, 0, stream>>>(S_row, S_ea, S_dinv, S_offs, rowArr, eaP, dinvF, offsF, E, N);
    k_zero32<<<1, 256, 0, stream>>>((unsigned int*)diag, 256);
    k_precheckN<<<NB, 256, 0, stream>>>(offsF, S_cursor, dinvF, S_gflag, diag, N, E);
    k_precheckE<<<NBE, 256, 0, stream>>>(rowArr, diag, E, N);

    // ---- layers: even l -> dst = D(d_out), odd l -> dst = X; agg planes live in dst ----
    for (int l = 0; l < NLAYERS; ++l) {
        int even = (l % 2 == 0);
        u16* dst_hi = even ? sD_hi : sX_hi;
        u16* dst_lo = even ? sD_lo : sX_lo;
        const void* hinA; const u16* hin_lo; int hf32;
        if (l == 0) { hinA = (const void*)x; hin_lo = 0; hf32 = 1; }
        else if (even) { hinA = (const void*)sX_hi; hin_lo = sX_lo; hf32 = 0; }
        else { hinA = (const void*)sD_hi; hin_lo = sD_lo; hf32 = 0; }

        k_wsplit<<<64, 256, 0, stream>>>(mlp_w + (size_t)l * 512 * HID, wpH, wpL, colsum);
        k_agg<<<NBA, 256, 0, stream>>>(hinA, hin_lo, hf32, offsF, rowArr, eaP, dinvF,
                                       ew1 + (size_t)l * 128, ew2 + (size_t)l * 384,
                                       dst_hi, dst_lo, diag, N);
        MPNN_79044578115931_kernel<<<NBG, 256, 0, stream>>>(
            hinA, hin_lo, hf32, dst_hi, dst_lo, wpH, wpL,
            mlp_b + (size_t)l * HID, dst_hi, dst_lo, colsum, colsq, diag, N);
        k_bnscale<<<1, 256, 0, stream>>>(colsum, colsq,
                                         bn_g + (size_t)l * HID, bn_b + (size_t)l * HID,
                                         scaleF, shiftF, diag, N);
        int finalL = (l == NLAYERS - 1) ? 1 : 0;
        int relu = finalL ? 0 : 1;
        // final: expand planes (in d_out) -> fp32 into X buffer, then copy back to d_out
        k_bnapply<<<NBQ, 256, 0, stream>>>(dst_hi, dst_lo, scaleF, shiftF,
                                           (float*)d_in[0], finalL, relu, (int)P);
    }

    hipMemcpyAsync(d_out, d_in[0], P * 4, hipMemcpyDeviceToDevice, stream);
    k_encode<<<1, 64, 0, stream>>>(diag, (float*)d_out);
}